// Round 1
// baseline (741.140 us; speedup 1.0000x reference)
//
#include <hip/hip_runtime.h>
#include <hip/hip_bf16.h>
#include <math.h>

#define NODES 10000
#define NEDGE 320000
#define INDIM 512
#define CH    128

typedef float f32x4 __attribute__((ext_vector_type(4)));
typedef short s16x8 __attribute__((ext_vector_type(8)));
typedef short s16x4 __attribute__((ext_vector_type(4)));

// bf16 round-to-nearest-even via bit ops (matches __float2bfloat16 for finite vals)
__device__ __forceinline__ short f2bf(float f) {
    unsigned u = __float_as_uint(f);
    unsigned r = (u + 0x7fffu + ((u >> 16) & 1u)) >> 16;
    return (short)r;
}
__device__ __forceinline__ float bf2f(short s) {
    return __uint_as_float(((unsigned)(unsigned short)s) << 16);
}

// ---------------- CSR build ----------------
__global__ void init_kernel(int* deg, int* cursor) {
    int i = blockIdx.x * blockDim.x + threadIdx.x;
    if (i < NODES) { deg[i] = 1; cursor[i] = 0; }  // deg starts at 1 (self-loop)
}

__global__ void count_kernel(const int* __restrict__ ei, int* deg) {
    int e = blockIdx.x * blockDim.x + threadIdx.x;
    if (e < NEDGE) atomicAdd(&deg[ei[NEDGE + e]], 1);
}

// single-block scan over NODES entries; also computes dinv = rsqrt(deg)
__global__ __launch_bounds__(1024) void scan_kernel(const int* __restrict__ deg,
                                                    int* startArr, float* dinv) {
    __shared__ int s[1024];
    const int CHUNK = 10;  // 1024*10 >= 10000
    int t = threadIdx.x;
    int i0 = t * CHUNK;
    int local = 0;
    for (int j = 0; j < CHUNK; j++) {
        int i = i0 + j;
        if (i < NODES) local += deg[i] - 1;  // edge-only count
    }
    s[t] = local;
    __syncthreads();
    for (int off = 1; off < 1024; off <<= 1) {
        int v = (t >= off) ? s[t - off] : 0;
        __syncthreads();
        s[t] += v;
        __syncthreads();
    }
    int run = s[t] - local;  // exclusive prefix
    for (int j = 0; j < CHUNK; j++) {
        int i = i0 + j;
        if (i < NODES) {
            startArr[i] = run;
            run += deg[i] - 1;
            dinv[i] = rsqrtf((float)deg[i]);
        }
    }
    if (t == 1023) startArr[NODES] = run;  // == NEDGE
}

__global__ void fill_kernel(const int* __restrict__ ei, const int* __restrict__ startArr,
                            int* cursor, int* perm) {
    int e = blockIdx.x * blockDim.x + threadIdx.x;
    if (e < NEDGE) {
        int d = ei[NEDGE + e];
        int pos = atomicAdd(&cursor[d], 1);
        perm[startArr[d] + pos] = e;
    }
}

// ---------------- split-bf16 MFMA GEMM: out[M][128] = A[M][K] @ W[128][K]^T ----------------
// block = 256 thr (4 waves); block tile 64 rows x 128 cols; wave tile 16 x 128.
template <bool L2N>
__global__ __launch_bounds__(256) void gemm_mfma(const float* __restrict__ A,
                                                 const float* __restrict__ W,
                                                 const float* __restrict__ bias,
                                                 float* __restrict__ out, int M, int K) {
    const int SROW = 72;  // padded LDS row (bf16 elems): 144B -> 2-way-free banks, 16B aligned
    __shared__ short Ah[64 * SROW], Al[64 * SROW];
    __shared__ short Bh[128 * SROW], Bl[128 * SROW];

    int tid = threadIdx.x;
    int row0 = blockIdx.x * 64;
    int wave = tid >> 6, lane = tid & 63;
    int quad = lane >> 4, l16 = lane & 15;

    f32x4 acc[8];
    for (int t = 0; t < 8; t++) acc[t] = (f32x4){0.f, 0.f, 0.f, 0.f};

    for (int kb = 0; kb < K; kb += 64) {
        __syncthreads();
        // stage A tile: 64 rows x 64 k (fp32 -> bf16 hi/lo)
        for (int i = 0; i < 4; i++) {
            int idx = tid + 256 * i;
            int j = idx & 15, r = idx >> 4;
            float4 v = {0.f, 0.f, 0.f, 0.f};
            int grow = row0 + r;
            if (grow < M) v = *(const float4*)(A + (size_t)grow * K + kb + 4 * j);
            float vv[4] = {v.x, v.y, v.z, v.w};
            s16x4 h4, l4;
            for (int q = 0; q < 4; q++) {
                short hs = f2bf(vv[q]);
                h4[q] = hs;
                l4[q] = f2bf(vv[q] - bf2f(hs));
            }
            *(s16x4*)&Ah[r * SROW + 4 * j] = h4;
            *(s16x4*)&Al[r * SROW + 4 * j] = l4;
        }
        // stage B tile: 128 n x 64 k
        for (int i = 0; i < 8; i++) {
            int idx = tid + 256 * i;
            int j = idx & 15, n = idx >> 4;
            float4 v = *(const float4*)(W + (size_t)n * K + kb + 4 * j);
            float vv[4] = {v.x, v.y, v.z, v.w};
            s16x4 h4, l4;
            for (int q = 0; q < 4; q++) {
                short hs = f2bf(vv[q]);
                h4[q] = hs;
                l4[q] = f2bf(vv[q] - bf2f(hs));
            }
            *(s16x4*)&Bh[n * SROW + 4 * j] = h4;
            *(s16x4*)&Bl[n * SROW + 4 * j] = l4;
        }
        __syncthreads();

        for (int kk = 0; kk < 64; kk += 32) {
            int aoff = (wave * 16 + l16) * SROW + kk + quad * 8;
            s16x8 ah = *(const s16x8*)&Ah[aoff];
            s16x8 al = *(const s16x8*)&Al[aoff];
            for (int t = 0; t < 8; t++) {
                int boff = (t * 16 + l16) * SROW + kk + quad * 8;
                s16x8 bh = *(const s16x8*)&Bh[boff];
                s16x8 bl = *(const s16x8*)&Bl[boff];
                acc[t] = __builtin_amdgcn_mfma_f32_16x16x32_bf16(ah, bh, acc[t], 0, 0, 0);
                acc[t] = __builtin_amdgcn_mfma_f32_16x16x32_bf16(ah, bl, acc[t], 0, 0, 0);
                acc[t] = __builtin_amdgcn_mfma_f32_16x16x32_bf16(al, bh, acc[t], 0, 0, 0);
            }
        }
    }

    // epilogue: C/D layout row = quad*4+reg, col = t*16 + l16
    if (bias) {
        for (int t = 0; t < 8; t++) {
            float bv = bias[t * 16 + l16];
            for (int r = 0; r < 4; r++) acc[t][r] += bv;
        }
    }
    if (L2N) {
        for (int r = 0; r < 4; r++) {
            float ss = 0.f;
            for (int t = 0; t < 8; t++) ss += acc[t][r] * acc[t][r];
            for (int off = 1; off < 16; off <<= 1) ss += __shfl_xor(ss, off, 64);
            float scale = 1.8f / fmaxf(sqrtf(ss), 1e-12f);
            for (int t = 0; t < 8; t++) acc[t][r] *= scale;
        }
    }
    for (int r = 0; r < 4; r++) {
        int grow = row0 + wave * 16 + quad * 4 + r;
        if (grow < M)
            for (int t = 0; t < 8; t++)
                out[(size_t)grow * CH + t * 16 + l16] = acc[t][r];
    }
}

// ---------------- GCN aggregation: one wave per node (pull via CSR) ----------------
__global__ __launch_bounds__(256) void agg_kernel(const float* __restrict__ xw,
                                                  const float* __restrict__ dinv,
                                                  const int* __restrict__ ei,
                                                  const int* __restrict__ perm,
                                                  const int* __restrict__ startArr,
                                                  const float* __restrict__ bg,
                                                  float* __restrict__ z1) {
    int node = (blockIdx.x * blockDim.x + threadIdx.x) >> 6;
    int lane = threadIdx.x & 63;
    if (node >= NODES) return;
    float di = dinv[node];
    float2 v = *(const float2*)(xw + (size_t)node * CH + 2 * lane);
    float selfc = di * di;
    float ax = v.x * selfc, ay = v.y * selfc;
    int s = startArr[node], e = startArr[node + 1];
    for (int i = s; i < e; i++) {
        int eid = perm[i];
        int src = ei[eid];
        float coeff = dinv[src] * di;
        float2 u = *(const float2*)(xw + (size_t)src * CH + 2 * lane);
        ax += u.x * coeff;
        ay += u.y * coeff;
    }
    float2 b = *(const float2*)(bg + 2 * lane);
    z1[(size_t)node * CH + 2 * lane] = ax + b.x;
    z1[(size_t)node * CH + 2 * lane + 1] = ay + b.y;
}

// ---------------- z2 column 0: one block per x2 row (400MB stream, the HBM floor) ----------------
__global__ __launch_bounds__(256) void z2_kernel(const float* __restrict__ x2,
                                                 const float* __restrict__ W22,
                                                 float* __restrict__ z2v) {
    int row = blockIdx.x;
    const float4* xr = (const float4*)(x2 + (size_t)row * NODES);
    const float4* w0 = (const float4*)(W22);
    const float4* w1 = (const float4*)(W22 + NODES);
    float s0 = 0.f, s1 = 0.f;
    for (int j = threadIdx.x; j < NODES / 4; j += 256) {
        float4 v = xr[j];
        float4 a = w0[j];
        float4 b = w1[j];
        s0 += v.x * a.x + v.y * a.y + v.z * a.z + v.w * a.w;
        s1 += v.x * b.x + v.y * b.y + v.z * b.z + v.w * b.w;
    }
    for (int off = 1; off < 64; off <<= 1) {
        s0 += __shfl_xor(s0, off, 64);
        s1 += __shfl_xor(s1, off, 64);
    }
    __shared__ float r0[4], r1[4];
    int wave = threadIdx.x >> 6;
    if ((threadIdx.x & 63) == 0) { r0[wave] = s0; r1[wave] = s1; }
    __syncthreads();
    if (threadIdx.x == 0) {
        float v0 = r0[0] + r0[1] + r0[2] + r0[3];
        float v1 = r1[0] + r1[1] + r1[2] + r1[3];
        float n = sqrtf(v0 * v0 + v1 * v1);
        z2v[row] = 0.8f * v0 / fmaxf(n, 1e-12f);
    }
}

// ---------------- edge scoring: 32 lanes per edge ----------------
__global__ __launch_bounds__(256) void score_kernel(const float* __restrict__ z1,
                                                    const float* __restrict__ z2v,
                                                    const int* __restrict__ ei,
                                                    float* __restrict__ out) {
    int g = threadIdx.x >> 5, l = threadIdx.x & 31;
    int e = blockIdx.x * 8 + g;
    if (e >= NEDGE) return;
    int r = ei[e], c = ei[NEDGE + e];
    float4 a = *(const float4*)(z1 + (size_t)r * CH + 4 * l);
    float4 b = *(const float4*)(z1 + (size_t)c * CH + 4 * l);
    float d = a.x * b.x + a.y * b.y + a.z * b.z + a.w * b.w;
    for (int off = 1; off < 32; off <<= 1) d += __shfl_xor(d, off, 64);
    if (l == 0) {
        float vn = z2v[r] + z2v[c];
        float sf = 1.f / (1.f + __expf(-d));
        float sn = 1.f / (1.f + __expf(-vn));
        out[e] = sf * sf + (1.f - sf) * sn;
    }
}

extern "C" void kernel_launch(void* const* d_in, const int* in_sizes, int n_in,
                              void* d_out, int out_size, void* d_ws, size_t ws_size,
                              hipStream_t stream) {
    const float* x   = (const float*)d_in[0];
    const float* x2  = (const float*)d_in[1];
    const float* W2  = (const float*)d_in[2];
    const float* b2  = (const float*)d_in[3];
    const float* Wg  = (const float*)d_in[4];
    const float* bg  = (const float*)d_in[5];
    const float* W22 = (const float*)d_in[6];
    const int*   ei  = (const int*)d_in[7];
    float* out = (float*)d_out;

    char* ws = (char*)d_ws;
    size_t off = 0;
    auto alloc = [&](size_t bytes) -> void* {
        void* p = ws + off;
        off = (off + bytes + 255) & ~(size_t)255;
        return p;
    };
    int*   deg      = (int*)alloc(NODES * 4);
    int*   cursor   = (int*)alloc(NODES * 4);
    int*   startArr = (int*)alloc((NODES + 1) * 4);
    float* dinv     = (float*)alloc(NODES * 4);
    int*   perm     = (int*)alloc(NEDGE * 4);
    float* h        = (float*)alloc((size_t)NODES * CH * 4);
    float* xw       = (float*)alloc((size_t)NODES * CH * 4);
    float* z1       = (float*)alloc((size_t)NODES * CH * 4);
    float* z2v      = (float*)alloc(NODES * 4);

    init_kernel<<<(NODES + 255) / 256, 256, 0, stream>>>(deg, cursor);
    count_kernel<<<(NEDGE + 255) / 256, 256, 0, stream>>>(ei, deg);
    scan_kernel<<<1, 1024, 0, stream>>>(deg, startArr, dinv);
    fill_kernel<<<(NEDGE + 255) / 256, 256, 0, stream>>>(ei, startArr, cursor, perm);

    int gblocks = (NODES + 63) / 64;
    gemm_mfma<true><<<gblocks, 256, 0, stream>>>(x, W2, b2, h, NODES, INDIM);
    gemm_mfma<false><<<gblocks, 256, 0, stream>>>(h, Wg, nullptr, xw, NODES, CH);

    agg_kernel<<<(NODES + 3) / 4, 256, 0, stream>>>(xw, dinv, ei, perm, startArr, bg, z1);
    z2_kernel<<<NODES, 256, 0, stream>>>(x2, W22, z2v);
    score_kernel<<<(NEDGE + 7) / 8, 256, 0, stream>>>(z1, z2v, ei, out);
}